// Round 28
// baseline (381.461 us; speedup 1.0000x reference)
//
#include <hip/hip_runtime.h>

typedef unsigned char u8;
typedef unsigned short u16;
typedef unsigned int u32;
using f32x4 = __attribute__((ext_vector_type(4))) float;
using i32x8 = __attribute__((ext_vector_type(8))) int;

#define EPSF 1e-8f

constexpr int C1 = 768;
constexpr int HW = 9216;       // 96*96
constexpr int CJ = 2304;       // joint channels (bytes/row in fp8; /2 in fp4)
constexpr int RB4 = CJ / 2;    // 1152 B per fp4 row
constexpr int NS = 36;         // col splits (9216/256)
constexpr int NTKR = 9;        // staging rounds of 256 k-elems (2304/256)

// async global->LDS DMA, 16B per lane. LDS dest = wave-uniform base + lane*16.
__device__ __forceinline__ void gl_lds16(const u8* g, u8* l) {
    __builtin_amdgcn_global_load_lds(
        (const __attribute__((address_space(1))) void*)g,
        (__attribute__((address_space(3))) void*)l, 16, 0, 0);
}

// e4m3fn -> f32 (no inf; NaN never occurs for our data)
__device__ __forceinline__ float e4m3f(u32 b) {
    u32 s = b >> 7, e = (b >> 3) & 15, m = b & 7;
    float mag = (e == 0) ? (float)m * 0.001953125f               // m * 2^-9
                         : __uint_as_float(((e + 120) << 23) | (m << 20));
    return s ? -mag : mag;
}

// f32 -> e2m1 (fp4) RNE. Magnitude codes 0..7 = {0,0.5,1,1.5,2,3,4,6}.
__device__ __forceinline__ u32 f2fp4(float v) {
    float a = fabsf(v);
    u32 s = (__float_as_uint(v) >> 31) << 3;
    u32 m = (a >= 0.25f) + (a >= 0.75f) + (a >= 1.25f) + (a >= 1.75f)
          + (a >= 2.5f) + (a >= 3.5f) + (a >= 5.0f);
    return s | m;
}

// ---------------- fused transpose + fp32->{fp8,fp4} + column sum-of-squares ----------------
__global__ void k_transq(const float* __restrict__ x, const float* __restrict__ s,
                         const float* __restrict__ rd, const float* __restrict__ sd,
                         const float* __restrict__ re, const float* __restrict__ se,
                         u8* __restrict__ CT8, u8* __restrict__ ST8,
                         u8* __restrict__ CT4, u8* __restrict__ ST4,
                         float* __restrict__ sq6) {
    __shared__ float tile[64][69];
    __shared__ float part[16][68];
    const int j0 = blockIdx.x * 64;
    const int c0 = blockIdx.y * 64;
    const int z = blockIdx.z;
    const int tid = threadIdx.x;                     // 256
    const int seg = (c0 >= 1536) ? 2 : (c0 >= 768) ? 1 : 0;   // 768%64==0: no straddle
    const float* src = (z == 0) ? (seg == 0 ? x : seg == 1 ? rd : re)
                                : (seg == 0 ? s : seg == 1 ? sd : se);
    u8* dst8 = (z == 0) ? CT8 : ST8;
    u8* dst4 = (z == 0) ? CT4 : ST4;
    const int cb = c0 - seg * 768;

    const int jq = tid & 15;
    const int cidx = tid >> 4;
    f32x4 ss4 = {0.f, 0.f, 0.f, 0.f};
#pragma unroll
    for (int r = 0; r < 4; ++r) {
        const int c = cidx + r * 16;
        const float4 v = *(const float4*)&src[(size_t)(cb + c) * HW + j0 + jq * 4];
        tile[c][jq * 4 + 0] = v.x; tile[c][jq * 4 + 1] = v.y;
        tile[c][jq * 4 + 2] = v.z; tile[c][jq * 4 + 3] = v.w;
        ss4[0] = fmaf(v.x, v.x, ss4[0]); ss4[1] = fmaf(v.y, v.y, ss4[1]);
        ss4[2] = fmaf(v.z, v.z, ss4[2]); ss4[3] = fmaf(v.w, v.w, ss4[3]);
    }
#pragma unroll
    for (int k = 0; k < 4; ++k) part[cidx][jq * 4 + k] = ss4[k];
    __syncthreads();
    if (tid < 64) {
        float t = 0.f;
#pragma unroll
        for (int k = 0; k < 16; ++k) t += part[k][tid];
        atomicAdd(&sq6[(size_t)(seg * 2 + z) * HW + j0 + tid], t);
    }
    // writes: thread -> row j = tid>>2, quarter q = tid&3 (16 c's)
    const int j = tid >> 2;
    const int q = tid & 3;
    u16 h[8];
#pragma unroll
    for (int k = 0; k < 8; ++k) {
        const int c = q * 16 + k * 2;
        h[k] = (u16)__builtin_amdgcn_cvt_pk_fp8_f32(tile[c][j], tile[c + 1][j], 0, false);
    }
    *(uint4*)(dst8 + (size_t)(j0 + j) * CJ + c0 + q * 16) = *(const uint4*)h;

    u32 p0 = 0, p1 = 0;
#pragma unroll
    for (int k = 0; k < 8; ++k) p0 |= f2fp4(tile[q * 16 + k][j]) << (4 * k);
#pragma unroll
    for (int k = 0; k < 8; ++k) p1 |= f2fp4(tile[q * 16 + 8 + k][j]) << (4 * k);
    uint2 pp; pp.x = p0; pp.y = p1;
    *(uint2*)(dst4 + (size_t)(j0 + j) * RB4 + c0 / 2 + q * 8) = pp;
}

// ---------------- norms: inv6[m][j] = 1/(sqrt(sq)+eps); joint style norm ----------------
__global__ void k_norms(const float* __restrict__ sq6, float* __restrict__ inv6,
                        float* __restrict__ invbnj) {
    const int j = blockIdx.x * 256 + threadIdx.x;
#pragma unroll
    for (int m = 0; m < 6; ++m)
        inv6[(size_t)m * HW + j] = 1.0f / (sqrtf(sq6[(size_t)m * HW + j]) + EPSF);
    float sjoint = sq6[1 * HW + j] + sq6[3 * HW + j] + sq6[5 * HW + j];
    invbnj[j] = 1.0f / (sqrtf(sjoint + EPSF) + EPSF);
}

// ---------------- fused GEMM (G = CT^T*ST via MX-fp4 MFMA K=128) + per-row arg best/worst ----
// r24 structure (best measured GEMM: ~163-166us): 128Mx256N tile, 8 waves (2x4, 64x64),
// BK=256 2-barrier loop, no index tie-breaking in argmin/argmax merges.
__global__ __launch_bounds__(512, 2) void k_gemm_arg(
    const u8* __restrict__ CT4, const u8* __restrict__ ST4,
    const float* __restrict__ invbn,
    float* __restrict__ bestv, int* __restrict__ besti,
    float* __restrict__ worstv, int* __restrict__ worsti) {
    __shared__ __align__(16) u8 lds[49152];          // [A4: 16KB][B4: 32KB]
    u8* ldsA = lds;
    u8* ldsB = lds + 16384;
    float* s_bv = (float*)lds;                       // [4][128] alias ldsA (post-K only)
    int*   s_bi = (int*)(lds + 2048);
    float* s_wv = (float*)(lds + 4096);
    int*   s_wi = (int*)(lds + 6144);

    const int tid = threadIdx.x;
    const int l = tid & 63;
    const int w = tid >> 6;          // 0..7
    const int wr = w >> 2;           // 0..1  (M half, 64 rows)
    const int wc = w & 3;            // 0..3  (N quarter, 64 cols)
    const int rowbase = blockIdx.x * 128;
    const int colbase = blockIdx.y * 256;

    const int srow8 = l >> 3;
    const int sslot8 = (l & 7) ^ (l >> 3);
    const u8* gA = CT4 + (size_t)(rowbase + w * 16 + srow8) * RB4 + sslot8 * 16;
    const u8* gB = ST4 + (size_t)(colbase + w * 32 + srow8) * RB4 + sslot8 * 16;
    const int ldsAbase = w * 16 * 128;   // wave-uniform
    const int ldsBbase = w * 32 * 128;

    const int frow = l & 15;
    const int fk = l >> 4;
    const int r7f = frow & 7;
    const int sb0 = ((fk) ^ r7f) * 16;          // step 0 slot byte offset
    const int sb1 = ((4 + fk) ^ r7f) * 16;      // step 1
    const int arow = (wr * 64 + frow) * 128;    // + M*16*128
    const int brow = (wc * 64 + frow) * 128;    // + N*16*128

    f32x4 acc[4][4];
    const f32x4 fzero = {0.f, 0.f, 0.f, 0.f};
#pragma unroll
    for (int M = 0; M < 4; ++M)
#pragma unroll
        for (int N = 0; N < 4; ++N) acc[M][N] = fzero;

#define KSTEP(sb) {                                                           \
        i32x8 bfr[4], fA[4];                                                  \
        _Pragma("unroll")                                                     \
        for (int N = 0; N < 4; ++N)                                           \
            *(uint4*)&bfr[N] = *(const uint4*)(ldsB + brow + N * 16 * 128 + (sb)); \
        _Pragma("unroll")                                                     \
        for (int M = 0; M < 4; ++M)                                           \
            *(uint4*)&fA[M] = *(const uint4*)(ldsA + arow + M * 16 * 128 + (sb)); \
        _Pragma("unroll")                                                     \
        for (int M = 0; M < 4; ++M)                                           \
            _Pragma("unroll")                                                 \
            for (int N = 0; N < 4; ++N)                                       \
                acc[M][N] = __builtin_amdgcn_mfma_scale_f32_16x16x128_f8f6f4( \
                    fA[M], bfr[N], acc[M][N], 4, 4, 0, 0x7f7f7f7f, 0, 0x7f7f7f7f); }

#pragma unroll 1
    for (int t = 0; t < NTKR; ++t) {
        __syncthreads();                         // prior round's LDS reads done
        const size_t ko = (size_t)t * 128;       // 256 k-elems = 128 B fp4
#pragma unroll
        for (int c = 0; c < 2; ++c)
            gl_lds16(gA + ko + (size_t)c * 8 * RB4, ldsA + ldsAbase + c * 1024);
#pragma unroll
        for (int c = 0; c < 4; ++c)
            gl_lds16(gB + ko + (size_t)c * 8 * RB4, ldsB + ldsBbase + c * 1024);
        __syncthreads();                         // vmcnt(0) drain; other blocks overlap
        KSTEP(sb0);
        KSTEP(sb1);
    }
#undef KSTEP

    // epilogue: score = G * invbn[col]; per-row best/worst (C/D: col=l&15, row=(l>>4)*4+i)
    float ib[4];
#pragma unroll
    for (int N = 0; N < 4; ++N) ib[N] = invbn[colbase + wc * 64 + N * 16 + frow];

    __syncthreads();                             // K-loop LDS reads all done: alias safe

#pragma unroll
    for (int M = 0; M < 4; ++M) {
#pragma unroll
        for (int i = 0; i < 4; ++i) {
            float bv = -3.4e38f, wv = 3.4e38f; int bi = 0, wi = 0;
#pragma unroll
            for (int N = 0; N < 4; ++N) {
                float sc = acc[M][N][i] * ib[N];
                int ci = colbase + wc * 64 + N * 16 + frow;
                if (sc > bv) { bv = sc; bi = ci; }
                if (sc < wv) { wv = sc; wi = ci; }
            }
#pragma unroll
            for (int d = 1; d < 16; d <<= 1) {   // reduce across 16 col lanes (no tie-break)
                float obv = __shfl_xor(bv, d); int obi = __shfl_xor(bi, d);
                if (obv > bv) { bv = obv; bi = obi; }
                float owv = __shfl_xor(wv, d); int owi = __shfl_xor(wi, d);
                if (owv < wv) { wv = owv; wi = owi; }
            }
            if ((l & 15) == 0) {                 // each (wc,rl) written by exactly one lane
                int rl = wr * 64 + M * 16 + (l >> 4) * 4 + i;
                s_bv[wc * 128 + rl] = bv; s_bi[wc * 128 + rl] = bi;
                s_wv[wc * 128 + rl] = wv; s_wi[wc * 128 + rl] = wi;
            }
        }
    }

    __syncthreads();
    if (tid < 128) {
        float bv = s_bv[tid]; int bi = s_bi[tid];
        float wv = s_wv[tid]; int wi = s_wi[tid];
#pragma unroll
        for (int c = 1; c < 4; ++c) {
            float b2 = s_bv[c * 128 + tid]; int i2 = s_bi[c * 128 + tid];
            float w2 = s_wv[c * 128 + tid]; int j2 = s_wi[c * 128 + tid];
            if (b2 > bv) { bv = b2; bi = i2; }
            if (w2 < wv) { wv = w2; wi = j2; }
        }
        const int sp = blockIdx.y;
        bestv [(size_t)sp * HW + rowbase + tid] = bv;
        besti [(size_t)sp * HW + rowbase + tid] = bi;
        worstv[(size_t)sp * HW + rowbase + tid] = wv;
        worsti[(size_t)sp * HW + rowbase + tid] = wi;
    }
}

// ---------------- final: reduce splits (36), gathered cosines (fp8 rows), loss ----------------
// Round 28: TWO ROWS PER WAVE — both rows' reduce-loads (8 scattered) and both
// gathers (54 u32) issued in one exposure each: 2x memory-level parallelism per
// wave. r27 proved intra-row load batching was already done by the compiler;
// the remaining latency cost is per-wave exposure count, amortized here.
__global__ void k_final(const u8* __restrict__ CT, const u8* __restrict__ ST,
                        const float* __restrict__ inv6,
                        const float* __restrict__ bestv, const int* __restrict__ besti,
                        const float* __restrict__ worstv, const int* __restrict__ worsti,
                        float* __restrict__ out) {
    const int w = threadIdx.x >> 6, l = threadIdx.x & 63;
    const int r0 = blockIdx.x * 8 + w * 2;
    const int r1 = r0 + 1;

    float bv0 = -3.4e38f, wv0 = 3.4e38f; int bi0 = 0, wi0 = 0;
    float bv1 = -3.4e38f, wv1 = 3.4e38f; int bi1 = 0, wi1 = 0;
    if (l < NS) {
        bv0 = bestv [(size_t)l * HW + r0]; bi0 = besti [(size_t)l * HW + r0];
        wv0 = worstv[(size_t)l * HW + r0]; wi0 = worsti[(size_t)l * HW + r0];
        bv1 = bestv [(size_t)l * HW + r1]; bi1 = besti [(size_t)l * HW + r1];
        wv1 = worstv[(size_t)l * HW + r1]; wi1 = worsti[(size_t)l * HW + r1];
    }
#pragma unroll
    for (int d = 1; d < 64; d <<= 1) {
        float o; int oi;
        o = __shfl_xor(bv0, d); oi = __shfl_xor(bi0, d); if (o > bv0) { bv0 = o; bi0 = oi; }
        o = __shfl_xor(wv0, d); oi = __shfl_xor(wi0, d); if (o < wv0) { wv0 = o; wi0 = oi; }
        o = __shfl_xor(bv1, d); oi = __shfl_xor(bi1, d); if (o > bv1) { bv1 = o; bi1 = oi; }
        o = __shfl_xor(wv1, d); oi = __shfl_xor(wi1, d); if (o < wv1) { wv1 = o; wi1 = oi; }
    }

    const u8* ar0 = CT + (size_t)r0 * CJ;
    const u8* bb0 = ST + (size_t)bi0 * CJ;
    const u8* bw0 = ST + (size_t)wi0 * CJ;
    const u8* ar1 = CT + (size_t)r1 * CJ;
    const u8* bb1 = ST + (size_t)bi1 * CJ;
    const u8* bw1 = ST + (size_t)wi1 * CJ;

    // phase 1: ALL 54 gathered u32s issued together (one latency exposure)
    u32 va0[9], vb0[9], vw0[9], va1[9], vb1[9], vw1[9];
#pragma unroll
    for (int it = 0; it < 9; ++it) {
        const int c = it * 256 + l * 4;
        va0[it] = *(const u32*)(ar0 + c); vb0[it] = *(const u32*)(bb0 + c); vw0[it] = *(const u32*)(bw0 + c);
        va1[it] = *(const u32*)(ar1 + c); vb1[it] = *(const u32*)(bb1 + c); vw1[it] = *(const u32*)(bw1 + c);
    }

    // phase 2: decode + accumulate both rows
    float db0[3] = {0.f, 0.f, 0.f}, dw0[3] = {0.f, 0.f, 0.f};
    float db1[3] = {0.f, 0.f, 0.f}, dw1[3] = {0.f, 0.f, 0.f};
#pragma unroll
    for (int it = 0; it < 9; ++it) {
        const int seg = it / 3;
#pragma unroll
        for (int q = 0; q < 4; ++q) {
            float a0 = e4m3f((va0[it] >> (8 * q)) & 0xff);
            db0[seg] = fmaf(a0, e4m3f((vb0[it] >> (8 * q)) & 0xff), db0[seg]);
            dw0[seg] = fmaf(a0, e4m3f((vw0[it] >> (8 * q)) & 0xff), dw0[seg]);
            float a1 = e4m3f((va1[it] >> (8 * q)) & 0xff);
            db1[seg] = fmaf(a1, e4m3f((vb1[it] >> (8 * q)) & 0xff), db1[seg]);
            dw1[seg] = fmaf(a1, e4m3f((vw1[it] >> (8 * q)) & 0xff), dw1[seg]);
        }
    }
#pragma unroll
    for (int d = 1; d < 64; d <<= 1) {
#pragma unroll
        for (int s = 0; s < 3; ++s) {
            db0[s] += __shfl_xor(db0[s], d); dw0[s] += __shfl_xor(dw0[s], d);
            db1[s] += __shfl_xor(db1[s], d); dw1[s] += __shfl_xor(dw1[s], d);
        }
    }
    if (l == 0) {
        float c0 = db0[0] * inv6[0 * HW + r0] * inv6[1 * HW + bi0]
                 + db0[1] * inv6[2 * HW + r0] * inv6[3 * HW + bi0]
                 + db0[2] * inv6[4 * HW + r0] * inv6[5 * HW + bi0];
        float d0 = dw0[0] * inv6[0 * HW + r0] * inv6[1 * HW + wi0]
                 + dw0[1] * inv6[2 * HW + r0] * inv6[3 * HW + wi0]
                 + dw0[2] * inv6[4 * HW + r0] * inv6[5 * HW + wi0];
        float c1 = db1[0] * inv6[0 * HW + r1] * inv6[1 * HW + bi1]
                 + db1[1] * inv6[2 * HW + r1] * inv6[3 * HW + bi1]
                 + db1[2] * inv6[4 * HW + r1] * inv6[5 * HW + bi1];
        float d1 = dw1[0] * inv6[0 * HW + r1] * inv6[1 * HW + wi1]
                 + dw1[1] * inv6[2 * HW + r1] * inv6[3 * HW + wi1]
                 + dw1[2] * inv6[4 * HW + r1] * inv6[5 * HW + wi1];
        float contrib = (12.0f - c0 - c1 + d0 + d1) * (1.0f / 9216.0f);
        atomicAdd(out, contrib);
    }
}

extern "C" void kernel_launch(void* const* d_in, const int* in_sizes, int n_in,
                              void* d_out, int out_size, void* d_ws, size_t ws_size,
                              hipStream_t stream) {
    const float* x  = (const float*)d_in[0];
    const float* s  = (const float*)d_in[1];
    const float* rd = (const float*)d_in[2];
    const float* sd = (const float*)d_in[3];
    const float* re = (const float*)d_in[4];
    const float* se = (const float*)d_in[5];

    char* ws = (char*)d_ws;
    const size_t SZ8 = (size_t)HW * CJ;              // 21,233,664 B each (fp8)
    const size_t SZ4 = (size_t)HW * RB4;             // 10,616,832 B each (fp4)
    u8*    CT8    = (u8*)ws;
    u8*    ST8    = (u8*)(ws + SZ8);
    u8*    CT4    = (u8*)(ws + 2 * SZ8);
    u8*    ST4    = (u8*)(ws + 2 * SZ8 + SZ4);
    float* sq6    = (float*)(ws + 2 * SZ8 + 2 * SZ4);   // 6*HW floats
    float* inv6   = sq6 + 6 * HW;                    // 6*HW floats
    float* invbnj = inv6 + 6 * HW;                   // HW floats
    float* bestv  = invbnj + HW;                     // NS*HW floats
    int*   besti  = (int*)(bestv + (size_t)NS * HW);
    float* worstv = (float*)(besti + (size_t)NS * HW);
    int*   worsti = (int*)(worstv + (size_t)NS * HW);
    const size_t NEED = 2 * SZ8 + 2 * SZ4 + (size_t)(13 + 4 * NS) * HW * 4;
    if (ws_size < NEED) return;  // ws too small: fail loudly (wrong output)

    hipMemsetAsync(d_out, 0, sizeof(float), stream);
    hipMemsetAsync(sq6, 0, (size_t)6 * HW * 4, stream);   // k_transq accumulates atomically

    k_transq<<<dim3(HW / 64, CJ / 64, 2), 256, 0, stream>>>(
        x, s, rd, sd, re, se, CT8, ST8, CT4, ST4, sq6);
    k_norms<<<HW / 256, 256, 0, stream>>>(sq6, inv6, invbnj);
    k_gemm_arg<<<dim3(HW / 128, HW / 256), 512, 0, stream>>>(CT4, ST4, invbnj, bestv, besti, worstv, worsti);
    k_final<<<HW / 8, 256, 0, stream>>>(CT8, ST8, inv6, bestv, besti, worstv, worsti, (float*)d_out);
}

// Round 29
// 290.053 us; speedup vs baseline: 1.3151x; 1.3151x over previous
//
#include <hip/hip_runtime.h>

typedef unsigned char u8;
typedef unsigned short u16;
typedef unsigned int u32;
using f32x4 = __attribute__((ext_vector_type(4))) float;
using i32x8 = __attribute__((ext_vector_type(8))) int;

#define EPSF 1e-8f

constexpr int C1 = 768;
constexpr int HW = 9216;       // 96*96
constexpr int CJ = 2304;       // joint channels (bytes/row in fp8; /2 in fp4)
constexpr int RB4 = CJ / 2;    // 1152 B per fp4 row
constexpr int NS = 36;         // col splits (9216/256)
constexpr int NTKR = 9;        // staging rounds of 256 k-elems (2304/256)

// async global->LDS DMA, 16B per lane. LDS dest = wave-uniform base + lane*16.
__device__ __forceinline__ void gl_lds16(const u8* g, u8* l) {
    __builtin_amdgcn_global_load_lds(
        (const __attribute__((address_space(1))) void*)g,
        (__attribute__((address_space(3))) void*)l, 16, 0, 0);
}

// e4m3fn -> f32 (no inf; NaN never occurs for our data)
__device__ __forceinline__ float e4m3f(u32 b) {
    u32 s = b >> 7, e = (b >> 3) & 15, m = b & 7;
    float mag = (e == 0) ? (float)m * 0.001953125f               // m * 2^-9
                         : __uint_as_float(((e + 120) << 23) | (m << 20));
    return s ? -mag : mag;
}

// f32 -> e2m1 (fp4) RNE. Magnitude codes 0..7 = {0,0.5,1,1.5,2,3,4,6}.
__device__ __forceinline__ u32 f2fp4(float v) {
    float a = fabsf(v);
    u32 s = (__float_as_uint(v) >> 31) << 3;
    u32 m = (a >= 0.25f) + (a >= 0.75f) + (a >= 1.25f) + (a >= 1.75f)
          + (a >= 2.5f) + (a >= 3.5f) + (a >= 5.0f);
    return s | m;
}

// ---------------- fused transpose + fp32->{fp8,fp4} + column sum-of-squares ----------------
__global__ void k_transq(const float* __restrict__ x, const float* __restrict__ s,
                         const float* __restrict__ rd, const float* __restrict__ sd,
                         const float* __restrict__ re, const float* __restrict__ se,
                         u8* __restrict__ CT8, u8* __restrict__ ST8,
                         u8* __restrict__ CT4, u8* __restrict__ ST4,
                         float* __restrict__ sq6) {
    __shared__ float tile[64][69];
    __shared__ float part[16][68];
    const int j0 = blockIdx.x * 64;
    const int c0 = blockIdx.y * 64;
    const int z = blockIdx.z;
    const int tid = threadIdx.x;                     // 256
    const int seg = (c0 >= 1536) ? 2 : (c0 >= 768) ? 1 : 0;   // 768%64==0: no straddle
    const float* src = (z == 0) ? (seg == 0 ? x : seg == 1 ? rd : re)
                                : (seg == 0 ? s : seg == 1 ? sd : se);
    u8* dst8 = (z == 0) ? CT8 : ST8;
    u8* dst4 = (z == 0) ? CT4 : ST4;
    const int cb = c0 - seg * 768;

    const int jq = tid & 15;
    const int cidx = tid >> 4;
    f32x4 ss4 = {0.f, 0.f, 0.f, 0.f};
#pragma unroll
    for (int r = 0; r < 4; ++r) {
        const int c = cidx + r * 16;
        const float4 v = *(const float4*)&src[(size_t)(cb + c) * HW + j0 + jq * 4];
        tile[c][jq * 4 + 0] = v.x; tile[c][jq * 4 + 1] = v.y;
        tile[c][jq * 4 + 2] = v.z; tile[c][jq * 4 + 3] = v.w;
        ss4[0] = fmaf(v.x, v.x, ss4[0]); ss4[1] = fmaf(v.y, v.y, ss4[1]);
        ss4[2] = fmaf(v.z, v.z, ss4[2]); ss4[3] = fmaf(v.w, v.w, ss4[3]);
    }
#pragma unroll
    for (int k = 0; k < 4; ++k) part[cidx][jq * 4 + k] = ss4[k];
    __syncthreads();
    if (tid < 64) {
        float t = 0.f;
#pragma unroll
        for (int k = 0; k < 16; ++k) t += part[k][tid];
        atomicAdd(&sq6[(size_t)(seg * 2 + z) * HW + j0 + tid], t);
    }
    // writes: thread -> row j = tid>>2, quarter q = tid&3 (16 c's)
    const int j = tid >> 2;
    const int q = tid & 3;
    u16 h[8];
#pragma unroll
    for (int k = 0; k < 8; ++k) {
        const int c = q * 16 + k * 2;
        h[k] = (u16)__builtin_amdgcn_cvt_pk_fp8_f32(tile[c][j], tile[c + 1][j], 0, false);
    }
    *(uint4*)(dst8 + (size_t)(j0 + j) * CJ + c0 + q * 16) = *(const uint4*)h;

    u32 p0 = 0, p1 = 0;
#pragma unroll
    for (int k = 0; k < 8; ++k) p0 |= f2fp4(tile[q * 16 + k][j]) << (4 * k);
#pragma unroll
    for (int k = 0; k < 8; ++k) p1 |= f2fp4(tile[q * 16 + 8 + k][j]) << (4 * k);
    uint2 pp; pp.x = p0; pp.y = p1;
    *(uint2*)(dst4 + (size_t)(j0 + j) * RB4 + c0 / 2 + q * 8) = pp;
}

// ---------------- norms: inv6[m][j] = 1/(sqrt(sq)+eps); joint style norm ----------------
__global__ void k_norms(const float* __restrict__ sq6, float* __restrict__ inv6,
                        float* __restrict__ invbnj) {
    const int j = blockIdx.x * 256 + threadIdx.x;
#pragma unroll
    for (int m = 0; m < 6; ++m)
        inv6[(size_t)m * HW + j] = 1.0f / (sqrtf(sq6[(size_t)m * HW + j]) + EPSF);
    float sjoint = sq6[1 * HW + j] + sq6[3 * HW + j] + sq6[5 * HW + j];
    invbnj[j] = 1.0f / (sqrtf(sjoint + EPSF) + EPSF);
}

// ---------------- fused GEMM (G = CT^T*ST via MX-fp4 MFMA K=128) + per-row arg best/worst ----
// r24 structure (best measured GEMM: ~163-166us): 128Mx256N tile, 8 waves (2x4, 64x64),
// BK=256 2-barrier loop, no index tie-breaking in argmin/argmax merges.
__global__ __launch_bounds__(512, 2) void k_gemm_arg(
    const u8* __restrict__ CT4, const u8* __restrict__ ST4,
    const float* __restrict__ invbn,
    float* __restrict__ bestv, int* __restrict__ besti,
    float* __restrict__ worstv, int* __restrict__ worsti) {
    __shared__ __align__(16) u8 lds[49152];          // [A4: 16KB][B4: 32KB]
    u8* ldsA = lds;
    u8* ldsB = lds + 16384;
    float* s_bv = (float*)lds;                       // [4][128] alias ldsA (post-K only)
    int*   s_bi = (int*)(lds + 2048);
    float* s_wv = (float*)(lds + 4096);
    int*   s_wi = (int*)(lds + 6144);

    const int tid = threadIdx.x;
    const int l = tid & 63;
    const int w = tid >> 6;          // 0..7
    const int wr = w >> 2;           // 0..1  (M half, 64 rows)
    const int wc = w & 3;            // 0..3  (N quarter, 64 cols)
    const int rowbase = blockIdx.x * 128;
    const int colbase = blockIdx.y * 256;

    const int srow8 = l >> 3;
    const int sslot8 = (l & 7) ^ (l >> 3);
    const u8* gA = CT4 + (size_t)(rowbase + w * 16 + srow8) * RB4 + sslot8 * 16;
    const u8* gB = ST4 + (size_t)(colbase + w * 32 + srow8) * RB4 + sslot8 * 16;
    const int ldsAbase = w * 16 * 128;   // wave-uniform
    const int ldsBbase = w * 32 * 128;

    const int frow = l & 15;
    const int fk = l >> 4;
    const int r7f = frow & 7;
    const int sb0 = ((fk) ^ r7f) * 16;          // step 0 slot byte offset
    const int sb1 = ((4 + fk) ^ r7f) * 16;      // step 1
    const int arow = (wr * 64 + frow) * 128;    // + M*16*128
    const int brow = (wc * 64 + frow) * 128;    // + N*16*128

    f32x4 acc[4][4];
    const f32x4 fzero = {0.f, 0.f, 0.f, 0.f};
#pragma unroll
    for (int M = 0; M < 4; ++M)
#pragma unroll
        for (int N = 0; N < 4; ++N) acc[M][N] = fzero;

#define KSTEP(sb) {                                                           \
        i32x8 bfr[4], fA[4];                                                  \
        _Pragma("unroll")                                                     \
        for (int N = 0; N < 4; ++N)                                           \
            *(uint4*)&bfr[N] = *(const uint4*)(ldsB + brow + N * 16 * 128 + (sb)); \
        _Pragma("unroll")                                                     \
        for (int M = 0; M < 4; ++M)                                           \
            *(uint4*)&fA[M] = *(const uint4*)(ldsA + arow + M * 16 * 128 + (sb)); \
        _Pragma("unroll")                                                     \
        for (int M = 0; M < 4; ++M)                                           \
            _Pragma("unroll")                                                 \
            for (int N = 0; N < 4; ++N)                                       \
                acc[M][N] = __builtin_amdgcn_mfma_scale_f32_16x16x128_f8f6f4( \
                    fA[M], bfr[N], acc[M][N], 4, 4, 0, 0x7f7f7f7f, 0, 0x7f7f7f7f); }

#pragma unroll 1
    for (int t = 0; t < NTKR; ++t) {
        __syncthreads();                         // prior round's LDS reads done
        const size_t ko = (size_t)t * 128;       // 256 k-elems = 128 B fp4
#pragma unroll
        for (int c = 0; c < 2; ++c)
            gl_lds16(gA + ko + (size_t)c * 8 * RB4, ldsA + ldsAbase + c * 1024);
#pragma unroll
        for (int c = 0; c < 4; ++c)
            gl_lds16(gB + ko + (size_t)c * 8 * RB4, ldsB + ldsBbase + c * 1024);
        __syncthreads();                         // vmcnt(0) drain; other blocks overlap
        KSTEP(sb0);
        KSTEP(sb1);
    }
#undef KSTEP

    // epilogue: score = G * invbn[col]; per-row best/worst (C/D: col=l&15, row=(l>>4)*4+i)
    float ib[4];
#pragma unroll
    for (int N = 0; N < 4; ++N) ib[N] = invbn[colbase + wc * 64 + N * 16 + frow];

    __syncthreads();                             // K-loop LDS reads all done: alias safe

#pragma unroll
    for (int M = 0; M < 4; ++M) {
#pragma unroll
        for (int i = 0; i < 4; ++i) {
            float bv = -3.4e38f, wv = 3.4e38f; int bi = 0, wi = 0;
#pragma unroll
            for (int N = 0; N < 4; ++N) {
                float sc = acc[M][N][i] * ib[N];
                int ci = colbase + wc * 64 + N * 16 + frow;
                if (sc > bv) { bv = sc; bi = ci; }
                if (sc < wv) { wv = sc; wi = ci; }
            }
#pragma unroll
            for (int d = 1; d < 16; d <<= 1) {   // reduce across 16 col lanes (no tie-break)
                float obv = __shfl_xor(bv, d); int obi = __shfl_xor(bi, d);
                if (obv > bv) { bv = obv; bi = obi; }
                float owv = __shfl_xor(wv, d); int owi = __shfl_xor(wi, d);
                if (owv < wv) { wv = owv; wi = owi; }
            }
            if ((l & 15) == 0) {                 // each (wc,rl) written by exactly one lane
                int rl = wr * 64 + M * 16 + (l >> 4) * 4 + i;
                s_bv[wc * 128 + rl] = bv; s_bi[wc * 128 + rl] = bi;
                s_wv[wc * 128 + rl] = wv; s_wi[wc * 128 + rl] = wi;
            }
        }
    }

    __syncthreads();
    if (tid < 128) {
        float bv = s_bv[tid]; int bi = s_bi[tid];
        float wv = s_wv[tid]; int wi = s_wi[tid];
#pragma unroll
        for (int c = 1; c < 4; ++c) {
            float b2 = s_bv[c * 128 + tid]; int i2 = s_bi[c * 128 + tid];
            float w2 = s_wv[c * 128 + tid]; int j2 = s_wi[c * 128 + tid];
            if (b2 > bv) { bv = b2; bi = i2; }
            if (w2 < wv) { wv = w2; wi = j2; }
        }
        const int sp = blockIdx.y;
        bestv [(size_t)sp * HW + rowbase + tid] = bv;
        besti [(size_t)sp * HW + rowbase + tid] = bi;
        worstv[(size_t)sp * HW + rowbase + tid] = wv;
        worsti[(size_t)sp * HW + rowbase + tid] = wi;
    }
}

// ---------------- final: reduce splits (36), gathered cosines (fp8 rows), loss ----------------
// Round 29: r28's 2-rows-per-wave + __launch_bounds__(256). r28's k_final had NO
// launch bound -> compiler assumed 1024-thread blocks -> 64-VGPR cap -> the 54-u32
// gather arrays SPILLED (WRITE_SIZE 188MB in a read-only kernel). With 256 declared,
// the allocator may use up to 512 VGPRs; ~128 live regs, no LDS -> 16 waves/CU.
__global__ __launch_bounds__(256) void k_final(
    const u8* __restrict__ CT, const u8* __restrict__ ST,
    const float* __restrict__ inv6,
    const float* __restrict__ bestv, const int* __restrict__ besti,
    const float* __restrict__ worstv, const int* __restrict__ worsti,
    float* __restrict__ out) {
    const int w = threadIdx.x >> 6, l = threadIdx.x & 63;
    const int r0 = blockIdx.x * 8 + w * 2;
    const int r1 = r0 + 1;

    float bv0 = -3.4e38f, wv0 = 3.4e38f; int bi0 = 0, wi0 = 0;
    float bv1 = -3.4e38f, wv1 = 3.4e38f; int bi1 = 0, wi1 = 0;
    if (l < NS) {
        bv0 = bestv [(size_t)l * HW + r0]; bi0 = besti [(size_t)l * HW + r0];
        wv0 = worstv[(size_t)l * HW + r0]; wi0 = worsti[(size_t)l * HW + r0];
        bv1 = bestv [(size_t)l * HW + r1]; bi1 = besti [(size_t)l * HW + r1];
        wv1 = worstv[(size_t)l * HW + r1]; wi1 = worsti[(size_t)l * HW + r1];
    }
#pragma unroll
    for (int d = 1; d < 64; d <<= 1) {
        float o; int oi;
        o = __shfl_xor(bv0, d); oi = __shfl_xor(bi0, d); if (o > bv0) { bv0 = o; bi0 = oi; }
        o = __shfl_xor(wv0, d); oi = __shfl_xor(wi0, d); if (o < wv0) { wv0 = o; wi0 = oi; }
        o = __shfl_xor(bv1, d); oi = __shfl_xor(bi1, d); if (o > bv1) { bv1 = o; bi1 = oi; }
        o = __shfl_xor(wv1, d); oi = __shfl_xor(wi1, d); if (o < wv1) { wv1 = o; wi1 = oi; }
    }

    const u8* ar0 = CT + (size_t)r0 * CJ;
    const u8* bb0 = ST + (size_t)bi0 * CJ;
    const u8* bw0 = ST + (size_t)wi0 * CJ;
    const u8* ar1 = CT + (size_t)r1 * CJ;
    const u8* bb1 = ST + (size_t)bi1 * CJ;
    const u8* bw1 = ST + (size_t)wi1 * CJ;

    // phase 1: ALL 54 gathered u32s issued together (one latency exposure)
    u32 va0[9], vb0[9], vw0[9], va1[9], vb1[9], vw1[9];
#pragma unroll
    for (int it = 0; it < 9; ++it) {
        const int c = it * 256 + l * 4;
        va0[it] = *(const u32*)(ar0 + c); vb0[it] = *(const u32*)(bb0 + c); vw0[it] = *(const u32*)(bw0 + c);
        va1[it] = *(const u32*)(ar1 + c); vb1[it] = *(const u32*)(bb1 + c); vw1[it] = *(const u32*)(bw1 + c);
    }

    // phase 2: decode + accumulate both rows
    float db0[3] = {0.f, 0.f, 0.f}, dw0[3] = {0.f, 0.f, 0.f};
    float db1[3] = {0.f, 0.f, 0.f}, dw1[3] = {0.f, 0.f, 0.f};
#pragma unroll
    for (int it = 0; it < 9; ++it) {
        const int seg = it / 3;
#pragma unroll
        for (int q = 0; q < 4; ++q) {
            float a0 = e4m3f((va0[it] >> (8 * q)) & 0xff);
            db0[seg] = fmaf(a0, e4m3f((vb0[it] >> (8 * q)) & 0xff), db0[seg]);
            dw0[seg] = fmaf(a0, e4m3f((vw0[it] >> (8 * q)) & 0xff), dw0[seg]);
            float a1 = e4m3f((va1[it] >> (8 * q)) & 0xff);
            db1[seg] = fmaf(a1, e4m3f((vb1[it] >> (8 * q)) & 0xff), db1[seg]);
            dw1[seg] = fmaf(a1, e4m3f((vw1[it] >> (8 * q)) & 0xff), dw1[seg]);
        }
    }
#pragma unroll
    for (int d = 1; d < 64; d <<= 1) {
#pragma unroll
        for (int s = 0; s < 3; ++s) {
            db0[s] += __shfl_xor(db0[s], d); dw0[s] += __shfl_xor(dw0[s], d);
            db1[s] += __shfl_xor(db1[s], d); dw1[s] += __shfl_xor(dw1[s], d);
        }
    }
    if (l == 0) {
        float c0 = db0[0] * inv6[0 * HW + r0] * inv6[1 * HW + bi0]
                 + db0[1] * inv6[2 * HW + r0] * inv6[3 * HW + bi0]
                 + db0[2] * inv6[4 * HW + r0] * inv6[5 * HW + bi0];
        float d0 = dw0[0] * inv6[0 * HW + r0] * inv6[1 * HW + wi0]
                 + dw0[1] * inv6[2 * HW + r0] * inv6[3 * HW + wi0]
                 + dw0[2] * inv6[4 * HW + r0] * inv6[5 * HW + wi0];
        float c1 = db1[0] * inv6[0 * HW + r1] * inv6[1 * HW + bi1]
                 + db1[1] * inv6[2 * HW + r1] * inv6[3 * HW + bi1]
                 + db1[2] * inv6[4 * HW + r1] * inv6[5 * HW + bi1];
        float d1 = dw1[0] * inv6[0 * HW + r1] * inv6[1 * HW + wi1]
                 + dw1[1] * inv6[2 * HW + r1] * inv6[3 * HW + wi1]
                 + dw1[2] * inv6[4 * HW + r1] * inv6[5 * HW + wi1];
        float contrib = (12.0f - c0 - c1 + d0 + d1) * (1.0f / 9216.0f);
        atomicAdd(out, contrib);
    }
}

extern "C" void kernel_launch(void* const* d_in, const int* in_sizes, int n_in,
                              void* d_out, int out_size, void* d_ws, size_t ws_size,
                              hipStream_t stream) {
    const float* x  = (const float*)d_in[0];
    const float* s  = (const float*)d_in[1];
    const float* rd = (const float*)d_in[2];
    const float* sd = (const float*)d_in[3];
    const float* re = (const float*)d_in[4];
    const float* se = (const float*)d_in[5];

    char* ws = (char*)d_ws;
    const size_t SZ8 = (size_t)HW * CJ;              // 21,233,664 B each (fp8)
    const size_t SZ4 = (size_t)HW * RB4;             // 10,616,832 B each (fp4)
    u8*    CT8    = (u8*)ws;
    u8*    ST8    = (u8*)(ws + SZ8);
    u8*    CT4    = (u8*)(ws + 2 * SZ8);
    u8*    ST4    = (u8*)(ws + 2 * SZ8 + SZ4);
    float* sq6    = (float*)(ws + 2 * SZ8 + 2 * SZ4);   // 6*HW floats
    float* inv6   = sq6 + 6 * HW;                    // 6*HW floats
    float* invbnj = inv6 + 6 * HW;                   // HW floats
    float* bestv  = invbnj + HW;                     // NS*HW floats
    int*   besti  = (int*)(bestv + (size_t)NS * HW);
    float* worstv = (float*)(besti + (size_t)NS * HW);
    int*   worsti = (int*)(worstv + (size_t)NS * HW);
    const size_t NEED = 2 * SZ8 + 2 * SZ4 + (size_t)(13 + 4 * NS) * HW * 4;
    if (ws_size < NEED) return;  // ws too small: fail loudly (wrong output)

    hipMemsetAsync(d_out, 0, sizeof(float), stream);
    hipMemsetAsync(sq6, 0, (size_t)6 * HW * 4, stream);   // k_transq accumulates atomically

    k_transq<<<dim3(HW / 64, CJ / 64, 2), 256, 0, stream>>>(
        x, s, rd, sd, re, se, CT8, ST8, CT4, ST4, sq6);
    k_norms<<<HW / 256, 256, 0, stream>>>(sq6, inv6, invbnj);
    k_gemm_arg<<<dim3(HW / 128, HW / 256), 512, 0, stream>>>(CT4, ST4, invbnj, bestv, besti, worstv, worsti);
    k_final<<<HW / 8, 256, 0, stream>>>(CT8, ST8, inv6, bestv, besti, worstv, worsti, (float*)d_out);
}